// Round 11
// baseline (238.163 us; speedup 1.0000x reference)
//
#include <hip/hip_runtime.h>
#include <float.h>

#define HEADS 8
#define DIM 64
#define BATCH 2
#define SEQ 2048
#define KNN 32
#define QT 32
#define KT 64
#define NEGF (-3.402823466e38f)

typedef float f32x4 __attribute__((ext_vector_type(4)));
typedef __bf16 bf16x8 __attribute__((ext_vector_type(8)));

union F4 { float4 v; f32x4 e; float f[4]; };
union S8 { bf16x8 b; unsigned int u[4]; unsigned short us[8]; uint4 u4; uint2 u2[2]; };

__device__ __forceinline__ unsigned short f2bf(float x) {
    unsigned int u = __float_as_uint(x);
    u = (u + 0x7fffu + ((u >> 16) & 1u)) >> 16;
    return (unsigned short)u;
}

// ws layout (bytes), d_ws is 2 GiB:
//   flag  @ 0
//   knB   @ 1M    bf16 (B,S,D)     512 KB
//   vT    @ 1.5M  bf16 (B,D,S)     512 KB
//   maccG @ 2M    f32 (B,H,S,D)    8 MB   (mem-branch weighted V, unnormalized)
//   OL    @ 10M   f32 (B,H,S,D)    8 MB   (local-branch partial O, unnormalized)
//   mG @18M, lG @18M+128K, mLG @18M+256K, lLG @18M+384K   f32 (B,H,S) each

__global__ __launch_bounds__(256) void prep_kernel(const float* __restrict__ k,
                                                   const float* __restrict__ v,
                                                   const unsigned char* __restrict__ mmraw,
                                                   unsigned short* __restrict__ knB,
                                                   unsigned short* __restrict__ vT,
                                                   int* __restrict__ flag) {
    __shared__ float vt_s[64][65];
    const int w = threadIdx.x >> 6, lane = threadIdx.x & 63;
    const int s0 = blockIdx.x * 64;       // global row index b*SEQ+s
    const int b = s0 >> 11;
    for (int rr = 0; rr < 16; rr++) {
        const int sl = w * 16 + rr;
        const int row = s0 + sl;
        float kv = k[(size_t)row * DIM + lane];
        float ssq = kv * kv;
        #pragma unroll
        for (int m = 1; m < 64; m <<= 1) ssq += __shfl_xor(ssq, m);
        float kn = kv / fmaxf(sqrtf(ssq), 1e-12f);
        knB[(size_t)row * DIM + lane] = f2bf(kn);
        vt_s[sl][lane] = v[(size_t)row * DIM + lane];
    }
    __syncthreads();
    {
        const int d = threadIdx.x >> 2;
        const int sc = (threadIdx.x & 3) * 16;
        const int s_base = s0 & 2047;
        unsigned short tmp[16];
        #pragma unroll
        for (int e = 0; e < 16; e++) tmp[e] = f2bf(vt_s[sc + e][d]);
        unsigned short* dst = vT + ((size_t)b * DIM + d) * SEQ + s_base + sc;
        *(uint4*)dst = *(uint4*)&tmp[0];
        *(uint4*)(dst + 8) = *(uint4*)&tmp[8];
    }
    if (blockIdx.x == 0 && w == 0) {
        int bad = 0;
        #pragma unroll
        for (int t = 0; t < 8; t++) {
            int idx = t * 64 + lane;
            if ((idx & 3) != 0 && mmraw[idx] != 0) bad = 1;
        }
        unsigned long long anybad = __ballot(bad);
        if (lane == 0) flag[0] = (anybad == 0ULL) ? 1 : 0;
    }
}

// Fused kernel: block-role split. bid%9<8 -> mem-stream block (lane-owns-j, 1 row/wave);
// bid%9==8 -> flash block (writes unnormalized partials to ws). No inter-block deps:
// both roles co-resident per CU so flash compute hides mem stream latency.
__global__ __launch_bounds__(256, 4) void fused_kernel(
    const float* __restrict__ q,            // B,H,S,D
    const float* __restrict__ scale_param,  // H
    const float* __restrict__ mem_kv,       // B,H,S,KNN,2,D
    const void*  __restrict__ mem_mask,     // B,H,S,KNN
    const float* __restrict__ mask,         // B,S float (key mask)
    const unsigned short* __restrict__ knB, // B,S,D bf16
    const unsigned short* __restrict__ vT,  // B,D,S bf16
    const int*   __restrict__ flagp,
    float* __restrict__ maccG,              // B,H,S,D
    float* __restrict__ mG,                 // B,H,S
    float* __restrict__ lG,                 // B,H,S
    float* __restrict__ OL,                 // B,H,S,D
    float* __restrict__ mLG,                // B,H,S
    float* __restrict__ lLG)                // B,H,S
{
    __shared__ float qn_s[QT][DIM + 4];
    __shared__ float maccs[QT][DIM + 4];
    __shared__ unsigned short fragbuf[4][2][2][4][16][8];
    __shared__ float corr_s[4][QT];
    __shared__ float mlw[4][2][QT];
    __shared__ float qn_m[4][64];
    __shared__ float p_m[4][32];

    const int tid = threadIdx.x;
    const int w = tid >> 6;
    const int lane = tid & 63;
    const int g = lane >> 4;
    const int c = lane & 15;
    const int bid = blockIdx.x;
    const int r9 = bid % 9;

    if (r9 < 8) {
        // ---------------- MEM PATH (one row per wave) ----------------
        const int mid = (bid / 9) * 8 + r9;       // 0..8191
        const int gid = mid * 4 + w;              // 0..32767
        const int mask_is_int = flagp[0];
        const float scale = __expf(scale_param[(gid >> 11) & 7]);
        const float* rowp = mem_kv + (size_t)gid * (KNN * 2 * DIM);

        const int j1 = lane & 31, dh = lane >> 5;
        bool mybit;
        {
            size_t mmrow = (size_t)gid * KNN;
            mybit = mask_is_int ? (((const int*)mem_mask)[mmrow + j1] != 0)
                                : (((const unsigned char*)mem_mask)[mmrow + j1] != 0);
        }
        const unsigned int mb = (unsigned int)__ballot(mybit);

        float qv = q[(size_t)gid * DIM + lane];

        F4 dk[8];
        #pragma unroll
        for (int i = 0; i < 8; i++) dk[i].e = 0.f;
        {
            const float* kbase = rowp + j1 * (2 * DIM) + dh * 32;
            if (mybit) {
                #pragma unroll
                for (int i = 0; i < 8; i++) dk[i].e = *(const f32x4*)(kbase + 4 * i);
            }
        }
        F4 dv[8];
        #pragma unroll
        for (int t = 0; t < 8; t++) {
            dv[t].e = 0.f;
            const int j2 = 4 * t + g;
            if ((mb >> j2) & 1u)
                dv[t].e = *(const f32x4*)(rowp + j2 * (2 * DIM) + DIM + c * 4);
        }

        float ssq = qv * qv;
        #pragma unroll
        for (int m2 = 1; m2 < 64; m2 <<= 1) ssq += __shfl_xor(ssq, m2);
        float qn = qv / fmaxf(sqrtf(ssq), 1e-12f);
        qn_m[w][lane] = qn;

        float s = 0.f;
        #pragma unroll
        for (int i = 0; i < 8; i++) {
            F4 qq; qq.v = *(const float4*)&qn_m[w][dh * 32 + 4 * i];
            s += dk[i].f[0] * qq.f[0] + dk[i].f[1] * qq.f[1]
               + dk[i].f[2] * qq.f[2] + dk[i].f[3] * qq.f[3];
        }
        s += __shfl_xor(s, 32);
        s = mybit ? s * scale : NEGF;

        float mx = s;
        #pragma unroll
        for (int m2 = 1; m2 < 32; m2 <<= 1) mx = fmaxf(mx, __shfl_xor(mx, m2));
        float p = __expf(s - mx);
        float ls = p;
        #pragma unroll
        for (int m2 = 1; m2 < 32; m2 <<= 1) ls += __shfl_xor(ls, m2);
        if (lane < 32) p_m[w][lane] = p;

        f32x4 acc = 0.f;
        #pragma unroll
        for (int t = 0; t < 8; t++) {
            float pv = p_m[w][4 * t + g];
            #pragma unroll
            for (int e = 0; e < 4; e++) acc[e] += pv * dv[t].f[e];
        }
        #pragma unroll
        for (int e = 0; e < 4; e++) {
            acc[e] += __shfl_xor(acc[e], 16);
            acc[e] += __shfl_xor(acc[e], 32);
        }
        if (g == 0) {
            F4 o; o.e = acc;
            *(float4*)(maccG + (size_t)gid * DIM + c * 4) = o.v;
        }
        if (lane == 0) { mG[gid] = mx; lG[gid] = ls; }
        return;
    }

    // ---------------- FLASH PATH ----------------
    const int fid = bid / 9;              // 0..1023
    const int qt = 63 - (fid & 63);       // heavy tiles first
    const int bh = fid >> 6;
    const int b = bh >> 3;
    const int h = bh & 7;
    const int i0 = qt * QT;
    const float scale = __expf(scale_param[h]);

    // q-norm in-block (no dependency on mem blocks)
    for (int r = 0; r < 8; r++) {
        const int il = w * 8 + r;
        const int ig = i0 + il;
        float qv = q[((size_t)bh * SEQ + ig) * DIM + lane];
        float ssq = qv * qv;
        #pragma unroll
        for (int m2 = 1; m2 < 64; m2 <<= 1) ssq += __shfl_xor(ssq, m2);
        qn_s[il][lane] = qv / fmaxf(sqrtf(ssq), 1e-12f);
    }
    __syncthreads();

    bf16x8 qa[2][2];
    #pragma unroll
    for (int mt = 0; mt < 2; mt++)
        #pragma unroll
        for (int kc = 0; kc < 2; kc++) {
            const float* qp = &qn_s[mt * 16 + c][kc * 32 + g * 8];
            F4 a0, a1; a0.v = *(const float4*)qp; a1.v = *(const float4*)(qp + 4);
            S8 t;
            #pragma unroll
            for (int e = 0; e < 4; e++) { t.us[e] = f2bf(a0.f[e]); t.us[4 + e] = f2bf(a1.f[e]); }
            qa[mt][kc] = t.b;
        }

    f32x4 oacc[4][2];
    #pragma unroll
    for (int mtd = 0; mtd < 4; mtd++)
        #pragma unroll
        for (int ni = 0; ni < 2; ni++)
            #pragma unroll
            for (int r = 0; r < 4; r++) oacc[mtd][ni][r] = 0.f;
    float mrow[2][4], lrow[2][4];
    #pragma unroll
    for (int mt = 0; mt < 2; mt++)
        #pragma unroll
        for (int r = 0; r < 4; r++) { mrow[mt][r] = NEGF; lrow[mt][r] = 0.f; }

    const int nkt = ((i0 + QT - 1) >> 6) + 1;
    const unsigned short* knBb = knB + (size_t)b * SEQ * DIM;
    const unsigned short* vTb  = vT  + (size_t)b * DIM * SEQ;

    for (int jt = w; jt < nkt; jt += 4) {
        const int jb = jt * KT;

        bf16x8 va[4][2];
        #pragma unroll
        for (int mtd = 0; mtd < 4; mtd++)
            #pragma unroll
            for (int kk2 = 0; kk2 < 2; kk2++) {
                const unsigned short* vp = vTb + (size_t)(mtd * 16 + c) * SEQ + jb + kk2 * 32 + 4 * g;
                S8 t; t.u2[0] = *(const uint2*)vp; t.u2[1] = *(const uint2*)(vp + 16);
                va[mtd][kk2] = t.b;
            }

        f32x4 sacc[2][4];
        #pragma unroll
        for (int mt = 0; mt < 2; mt++)
            #pragma unroll
            for (int nt = 0; nt < 4; nt++)
                #pragma unroll
                for (int r = 0; r < 4; r++) sacc[mt][nt][r] = 0.f;
        #pragma unroll
        for (int kc = 0; kc < 2; kc++) {
            #pragma unroll
            for (int nt = 0; nt < 4; nt++) {
                S8 kb; kb.u4 = *(const uint4*)(knBb + (size_t)(jb + nt * 16 + c) * DIM + kc * 32 + g * 8);
                #pragma unroll
                for (int mt = 0; mt < 2; mt++)
                    sacc[mt][nt] = __builtin_amdgcn_mfma_f32_16x16x32_bf16(qa[mt][kc], kb.b, sacc[mt][nt], 0, 0, 0);
            }
        }

        float mv4[4];
        #pragma unroll
        for (int nt = 0; nt < 4; nt++) mv4[nt] = mask[b * SEQ + jb + nt * 16 + c];
        const bool docausal = (jb + 63 > i0);
        float corr[2][4];
        #pragma unroll
        for (int mt = 0; mt < 2; mt++) {
            #pragma unroll
            for (int nt = 0; nt < 4; nt++)
                #pragma unroll
                for (int r = 0; r < 4; r++) {
                    float s = sacc[mt][nt][r] * scale + NEGF * (1.f - mv4[nt]);
                    if (docausal) {
                        int j = jb + nt * 16 + c;
                        int i = i0 + mt * 16 + 4 * g + r;
                        if (j > i) s = NEGF;
                    }
                    sacc[mt][nt][r] = s;
                }
            #pragma unroll
            for (int r = 0; r < 4; r++) {
                float rmax = fmaxf(fmaxf(sacc[mt][0][r], sacc[mt][1][r]),
                                   fmaxf(sacc[mt][2][r], sacc[mt][3][r]));
                #pragma unroll
                for (int m2 = 1; m2 < 16; m2 <<= 1) rmax = fmaxf(rmax, __shfl_xor(rmax, m2));
                float mnew = fmaxf(mrow[mt][r], rmax);
                corr[mt][r] = __expf(mrow[mt][r] - mnew);
                mrow[mt][r] = mnew;
            }
        }

        #pragma unroll
        for (int mt = 0; mt < 2; mt++) {
            float psum[4] = {0.f, 0.f, 0.f, 0.f};
            #pragma unroll
            for (int nt = 0; nt < 4; nt++)
                #pragma unroll
                for (int r = 0; r < 4; r++) {
                    float p = __expf(sacc[mt][nt][r] - mrow[mt][r]);
                    psum[r] += p;
                    fragbuf[w][mt][nt >> 1][c >> 2][4 * g + r][(c & 3) + 4 * (nt & 1)] = f2bf(p);
                }
            #pragma unroll
            for (int r = 0; r < 4; r++) {
                float ps = psum[r];
                #pragma unroll
                for (int m2 = 1; m2 < 16; m2 <<= 1) ps += __shfl_xor(ps, m2);
                lrow[mt][r] = lrow[mt][r] * corr[mt][r] + ps;
            }
        }

        if (c == 0) {
            #pragma unroll
            for (int mt = 0; mt < 2; mt++)
                #pragma unroll
                for (int r = 0; r < 4; r++)
                    corr_s[w][mt * 16 + 4 * g + r] = corr[mt][r];
        }
        float cf0 = corr_s[w][c];
        float cf1 = corr_s[w][16 + c];
        #pragma unroll
        for (int mtd = 0; mtd < 4; mtd++)
            #pragma unroll
            for (int r = 0; r < 4; r++) { oacc[mtd][0][r] *= cf0; oacc[mtd][1][r] *= cf1; }

        #pragma unroll
        for (int kk2 = 0; kk2 < 2; kk2++)
            #pragma unroll
            for (int ni = 0; ni < 2; ni++) {
                S8 pb; pb.u4 = *(const uint4*)&fragbuf[w][ni][kk2][g][c][0];
                #pragma unroll
                for (int mtd = 0; mtd < 4; mtd++)
                    oacc[mtd][ni] = __builtin_amdgcn_mfma_f32_16x16x32_bf16(va[mtd][kk2], pb.b, oacc[mtd][ni], 0, 0, 0);
            }
    }

    // ---- combine 4 wave-partials into block partial; write O_local, m, l ----
    if (c == 0) {
        #pragma unroll
        for (int mt = 0; mt < 2; mt++)
            #pragma unroll
            for (int r = 0; r < 4; r++) {
                mlw[w][0][mt * 16 + 4 * g + r] = mrow[mt][r];
                mlw[w][1][mt * 16 + 4 * g + r] = lrow[mt][r];
            }
    }
    __syncthreads();
    {
        int i = tid >> 3;
        int d0 = (tid & 7) * 8;
        float mM = mlw[0][0][i];
        #pragma unroll
        for (int w2 = 1; w2 < 4; w2++) mM = fmaxf(mM, mlw[w2][0][i]);
        float L = 0.f;
        #pragma unroll
        for (int w2 = 0; w2 < 4; w2++) L += mlw[w2][1][i] * __expf(mlw[w2][0][i] - mM);
        #pragma unroll
        for (int e = 0; e < 8; e++) maccs[i][d0 + e] = 0.f;
        size_t row = (size_t)bh * SEQ + i0 + i;
        if ((tid & 7) == 0) { mLG[row] = mM; lLG[row] = L; }
        if ((tid & 7) == 1) corr_s[0][i] = mM;
    }
    __syncthreads();
    float ew0 = __expf(mlw[w][0][c]      - corr_s[0][c]);
    float ew1 = __expf(mlw[w][0][16 + c] - corr_s[0][16 + c]);
    for (int w2 = 0; w2 < 4; w2++) {
        if (w == w2) {
            #pragma unroll
            for (int mtd = 0; mtd < 4; mtd++)
                #pragma unroll
                for (int r = 0; r < 4; r++) {
                    maccs[c][mtd * 16 + 4 * g + r]      += oacc[mtd][0][r] * ew0;
                    maccs[16 + c][mtd * 16 + 4 * g + r] += oacc[mtd][1][r] * ew1;
                }
        }
        __syncthreads();
    }
    {
        int i = tid >> 3;
        int d0 = (tid & 7) * 8;
        float* op = OL + ((size_t)bh * SEQ + i0 + i) * DIM + d0;
        *(float4*)op       = *(const float4*)&maccs[i][d0];
        *(float4*)(op + 4) = *(const float4*)&maccs[i][d0 + 4];
    }
}

// Final merge of the two softmax groups.
__global__ __launch_bounds__(256) void merge_kernel(
    const float* __restrict__ OLp, const float* __restrict__ maccG,
    const float* __restrict__ mLG, const float* __restrict__ lLG,
    const float* __restrict__ mG,  const float* __restrict__ lG,
    float* __restrict__ out)
{
    const int row = blockIdx.x * 32 + (threadIdx.x >> 3);
    const int d0 = (threadIdx.x & 7) * 8;
    float ml = mLG[row], ll = lLG[row];
    float mg = mG[row],  lg = lG[row];
    float M = fmaxf(ml, mg);
    float el = __expf(ml - M);
    float em = __expf(mg - M);
    float inv = 1.f / (ll * el + lg * em);
    const float* ol = OLp  + (size_t)row * DIM + d0;
    const float* og = maccG + (size_t)row * DIM + d0;
    F4 a0, a1, b0, b1;
    a0.v = *(const float4*)ol;       a1.v = *(const float4*)(ol + 4);
    b0.v = *(const float4*)og;       b1.v = *(const float4*)(og + 4);
    F4 o0, o1;
    #pragma unroll
    for (int e = 0; e < 4; e++) {
        o0.f[e] = (a0.f[e] * el + b0.f[e] * em) * inv;
        o1.f[e] = (a1.f[e] * el + b1.f[e] * em) * inv;
    }
    float* op = out + (size_t)row * DIM + d0;
    *(float4*)op       = o0.v;
    *(float4*)(op + 4) = o1.v;
}

extern "C" void kernel_launch(void* const* d_in, const int* in_sizes, int n_in,
                              void* d_out, int out_size, void* d_ws, size_t ws_size,
                              hipStream_t stream) {
    const float* q           = (const float*)d_in[0];
    const float* k           = (const float*)d_in[1];
    const float* v           = (const float*)d_in[2];
    const float* scale_param = (const float*)d_in[3];
    const float* mem_kv      = (const float*)d_in[4];
    const float* mask        = (const float*)d_in[5];
    const void*  mem_mask    = d_in[6];
    float* out = (float*)d_out;

    char* base = (char*)d_ws;
    int* flag           = (int*)base;
    unsigned short* knB = (unsigned short*)(base + (1ull << 20));
    unsigned short* vT  = (unsigned short*)(base + (1ull << 20) + (512ull << 10));
    float* maccG        = (float*)(base + (2ull << 20));
    float* OL           = (float*)(base + (10ull << 20));
    float* mG           = (float*)(base + (18ull << 20));
    float* lG           = (float*)(base + (18ull << 20) + (128ull << 10));
    float* mLG          = (float*)(base + (18ull << 20) + (256ull << 10));
    float* lLG          = (float*)(base + (18ull << 20) + (384ull << 10));

    prep_kernel<<<dim3(BATCH * SEQ / 64), dim3(256), 0, stream>>>(
        k, v, (const unsigned char*)mem_mask, knB, vT, flag);
    fused_kernel<<<dim3(9216), dim3(256), 0, stream>>>(
        q, scale_param, mem_kv, mem_mask, mask, knB, vT, flag,
        maccG, mG, lG, OL, mLG, lLG);
    merge_kernel<<<dim3(BATCH * HEADS * SEQ / 32), dim3(256), 0, stream>>>(
        OL, maccG, mLG, lLG, mG, lG, out);
}